// Round 10
// baseline (280.455 us; speedup 1.0000x reference)
//
#include <hip/hip_runtime.h>
#include <stdint.h>

#define TOKENS 16384
#define KDIM 1024
#define QKVN 3072

typedef unsigned short u16;
using bf16x8 = __attribute__((ext_vector_type(8))) __bf16;
using f32x4  = __attribute__((ext_vector_type(4))) float;
using u16x8  = __attribute__((ext_vector_type(8))) unsigned short;

__device__ inline u16 f2bf(float f) {
  union { float f; uint32_t u; } v; v.f = f;
  uint32_t u = v.u;
  return (u16)((u + 0x7FFFu + ((u >> 16) & 1u)) >> 16);
}
__device__ inline float bf2f(u16 s) {
  union { uint32_t u; float f; } v; v.u = ((uint32_t)s) << 16;
  return v.f;
}
__device__ inline void g2l16(const void* g, void* l) {
  __builtin_amdgcn_global_load_lds(
      (const __attribute__((address_space(1))) void*)g,
      (__attribute__((address_space(3))) void*)l, 16, 0, 0);
}

// Stage one 128x64 bf16 half-tile (16 KB): 512 threads x 2 global_load_lds x 16B.
// Linear LDS dest; global source pre-swizzled so swizzled ds_reads are conflict-free.
template<int LD>
__device__ inline void stage_half(const u16* __restrict__ g, u16* l, int t) {
  #pragma unroll
  for (int i = 0; i < 2; ++i) {
    const int ch = i * 512 + t;          // 0..1023 chunks of 16B
    const int row = ch >> 3;             // 0..127
    const int cc = (ch & 7) ^ (row & 7); // source chunk pre-swizzle
    g2l16(g + (long)row * LD + cc * 8, (char*)l + ch * 16);
  }
}

// Fragment loads from a 128x64 half (16 KB); XOR-swizzled ds_read_b128.
#define LDA_H(DST, BASE) do { \
  _Pragma("unroll") \
  for (int mi = 0; mi < 4; ++mi) { \
    const int row = wm*64 + mi*16 + rl; \
    const char* p = (const char*)(BASE) + row*128; \
    const int sw = (row & 7) << 4; \
    DST[mi][0] = *(const bf16x8*)(p + ((kg*16) ^ sw)); \
    DST[mi][1] = *(const bf16x8*)(p + ((64 + kg*16) ^ sw)); \
  } \
} while (0)

#define LDB_H(DST, BASE) do { \
  _Pragma("unroll") \
  for (int ni = 0; ni < 2; ++ni) { \
    const int row = wn*32 + ni*16 + rl; \
    const char* p = (const char*)(BASE) + row*128; \
    const int sw = (row & 7) << 4; \
    DST[ni][0] = *(const bf16x8*)(p + ((kg*16) ^ sw)); \
    DST[ni][1] = *(const bf16x8*)(p + ((64 + kg*16) ^ sw)); \
  } \
} while (0)

// 16-MFMA group: one M-half x one B operand pair -> acc[.][NB..NB+1].
// kh-major: 8 independent chains per kh step.
#define MFMA_G(MH, AV, BV, NB) do { \
  _Pragma("unroll") \
  for (int kh = 0; kh < 2; ++kh) \
    _Pragma("unroll") \
    for (int mi = 0; mi < 4; ++mi) \
      _Pragma("unroll") \
      for (int ni = 0; ni < 2; ++ni) \
        acc[(MH)*4+mi][(NB)+ni] = __builtin_amdgcn_mfma_f32_16x16x32_bf16( \
            AV[mi][kh], BV[ni][kh], acc[(MH)*4+mi][(NB)+ni], 0, 0, 0); \
} while (0)

#define LGKM0 do { \
  asm volatile("s_waitcnt lgkmcnt(0)" ::: "memory"); \
  __builtin_amdgcn_sched_barrier(0); \
} while (0)
#define LGKM4 do { \
  asm volatile("s_waitcnt lgkmcnt(4)" ::: "memory"); \
  __builtin_amdgcn_sched_barrier(0); \
} while (0)
#define VMC(N) asm volatile("s_waitcnt vmcnt(" #N ")" ::: "memory")
#define BAR() __builtin_amdgcn_s_barrier()
#define SCHED0 __builtin_amdgcn_sched_barrier(0)
#define PRIO(N) __builtin_amdgcn_s_setprio(N)

// C = A(16384 x 1024 bf16, ld ALD) @ B^T (B stored N x 1024 bf16 rm).
// 256x256 tile, 8 waves (2Mx4N). 4 merged phases / 2-K-chunk iteration, ONE
// barrier per phase: {reads; stage; counted-lgkm; MFMA x32; vmcnt(4); BAR}.
// Hazards (verified r8/r9): stage at phase p targets slots whose last read was
// phase p-1 (readers drained own reads via lgkm before passing BAR(p-1));
// vmcnt(4) = own 4 DMA/phase -> slot staged at q landed by end q+1, read >= 3
// phases later. Heavy phases split MFMA into bA-group (starts at lgkmcnt(4),
// bB reads still draining) and bB-group (after lgkmcnt(0)).
// Tile bases precomputed outside the K-loop (no div in loop).
// EPI 0: QKV epilogue (phi cols<2048, mask on K cols), bf16 C (ld 3072), aux=mask
// EPI 1: plain fp32 C (ld NTOT)
template<int NTOT, int EPI, int ALD, int NT, int PERB>
__device__ __forceinline__ void gemm_body(
    const u16* __restrict__ A, const u16* __restrict__ Bm,
    void* __restrict__ C, const float* __restrict__ aux) {
  __shared__ u16 As[2][2][8192];   // [kchunk parity][row-half][128 x 64]
  __shared__ u16 Bs[2][2][8192];
  const int t = threadIdx.x;
  const int l = t & 63;
  const int w = t >> 6;
  const int rl = l & 15, kg = l >> 4;
  const int wm = w >> 2, wn = w & 3;      // 2M x 4N waves
  constexpr int nbn = NTOT / 256;
  constexpr int nwg = 64 * nbn;           // total output tiles
  constexpr int GRID = nwg / NT;          // blocks launched
  constexpr int KC = NT * 16;             // K-chunks (64 wide) per block
  constexpr int IT = KC / 2;              // iterations (2 chunks each)
  static_assert(nwg % 8 == 0, "bijective xcd swizzle");
  const int bid = blockIdx.x;

  auto tcoord = [&](int ot, long& tar, long& tbr) {
    const int gt = ot * GRID + bid;
    const int swz = (gt & 7) * (nwg / 8) + (gt >> 3);
    tar = (long)(swz / nbn) * 256;
    tbr = (long)(swz % nbn) * 256;
  };
  // Precompute tile bases (divisions OUT of the K-loop); runtime select via
  // ternary chains (cndmask), never runtime array indexing (rule #20).
  long ar0_, br0_, ar1_, br1_, ar2_, br2_;
  tcoord(0, ar0_, br0_);
  if (NT > 1) tcoord(1, ar1_, br1_); else { ar1_ = ar0_; br1_ = br0_; }
  if (NT > 2) tcoord(2, ar2_, br2_); else { ar2_ = ar1_; br2_ = br1_; }

  auto asrc = [&](int ch) {
    const int ti = ch >> 4;
    const long ta = (NT == 1 || ti == 0) ? ar0_ : (ti == 1 ? ar1_ : ar2_);
    return A + ta * ALD + (ch & 15) * 64;
  };
  auto bsrc = [&](int ch) {
    const int ti = ch >> 4;
    const long ta = (NT == 1 || ti == 0) ? ar0_ : (ti == 1 ? ar1_ : ar2_);
    const long tb = (NT == 1 || ti == 0) ? br0_ : (ti == 1 ? br1_ : br2_);
    return Bm + (PERB ? (ta >> 12) * 1048576 : 0) + tb * 1024 + (ch & 15) * 64;
  };

  f32x4 acc[8][4];
  #pragma unroll
  for (int i = 0; i < 8; ++i)
    #pragma unroll
    for (int j = 0; j < 4; ++j)
      acc[i][j] = (f32x4){0.f, 0.f, 0.f, 0.f};

  bf16x8 afA[4][2], bA[2][2], bB[2][2];

  auto epilogue = [&](int ot) {
    long ar0, br0; tcoord(ot, ar0, br0);
    #pragma unroll
    for (int mh = 0; mh < 2; ++mh)
      #pragma unroll
      for (int mi = 0; mi < 4; ++mi)
        #pragma unroll
        for (int j = 0; j < 4; ++j) {
          const long row = ar0 + mh*128 + wm*64 + mi*16 + kg*4 + j;
          float rs = 0.f;
          if (EPI == 0) rs = aux[row];            // mask[token]
          #pragma unroll
          for (int nh = 0; nh < 2; ++nh)
            #pragma unroll
            for (int ni = 0; ni < 2; ++ni) {
              const long col = br0 + nh*128 + wn*32 + ni*16 + rl;
              float v = acc[mh*4+mi][nh*2+ni][j];
              if (EPI == 0) {
                if (col < 2048) {                  // Q or K: phi = elu(x)+1
                  v = (v > 0.f) ? (v + 1.f) : __expf(v);
                  if (col >= 1024) v *= rs;        // K: * mask[token]
                }
                ((u16*)C)[row * QKVN + col] = f2bf(v);
              } else {
                ((float*)C)[row * NTOT + col] = v;
              }
            }
        }
    #pragma unroll
    for (int i = 0; i < 8; ++i)
      #pragma unroll
      for (int j = 0; j < 4; ++j)
        acc[i][j] = (f32x4){0.f, 0.f, 0.f, 0.f};
  };

  // Prologue: chunk0 all 4 halves + chunk1 h0 pair (h1 pair staged at mph1).
  {
    const u16* A0s = asrc(0); const u16* B0s = bsrc(0);
    const u16* A1s = asrc(1); const u16* B1s = bsrc(1);
    stage_half<ALD >(A0s,             As[0][0], t);
    stage_half<1024>(B0s,             Bs[0][0], t);
    stage_half<1024>(B0s + 128*1024,  Bs[0][1], t);
    stage_half<ALD >(A0s + 128*ALD,   As[0][1], t);
    stage_half<ALD >(A1s,             As[1][0], t);
    stage_half<1024>(B1s,             Bs[1][0], t);
    VMC(4);            // chunk0's 4 halves landed; chunk1 h0 pair in flight
    BAR();
  }

  for (int i = 0; i < IT; ++i) {
    const int o1 = 2*i + 1;
    const int e = (2*i + 2 < KC) ? 2*i + 2 : KC - 1;   // parity 0
    const int o = (2*i + 3 < KC) ? 2*i + 3 : KC - 1;   // parity 1
    const u16* Ao1 = asrc(o1); const u16* Bo1 = bsrc(o1);
    const u16* Ae = asrc(e);   const u16* Be = bsrc(e);
    const u16* Ao = asrc(o);   const u16* Bo = bsrc(o);

    // mph1: c0 M-half0 | stage c1 h1 pair (slots read prev mph3)
    LDA_H(afA, As[0][0]); LDB_H(bA, Bs[0][0]);
    SCHED0;                                   // pin: afA+bA are the oldest 12
    LDB_H(bB, Bs[0][1]);
    stage_half<ALD>(Ao1 + 128*ALD, As[1][1], t);
    stage_half<1024>(Bo1 + 128*1024, Bs[1][1], t);
    SCHED0;
    LGKM4;                                    // afA+bA done; bB draining
    PRIO(1); MFMA_G(0, afA, bA, 0);
    LGKM0;
    MFMA_G(0, afA, bB, 2); PRIO(0);
    VMC(4); BAR();

    // mph2: c0 M-half1 | stage e h0 pair (slots read mph1)
    LDA_H(afA, As[0][1]);
    stage_half<ALD>(Ae, As[0][0], t);
    stage_half<1024>(Be, Bs[0][0], t);
    SCHED0;
    LGKM0;
    PRIO(1); MFMA_G(1, afA, bA, 0); MFMA_G(1, afA, bB, 2); PRIO(0);
    VMC(4); BAR();

    // mph3: c1 M-half0 | stage e h1 pair (As[0][1] read mph2, Bs[0][1] read mph1)
    LDA_H(afA, As[1][0]); LDB_H(bA, Bs[1][0]);
    SCHED0;
    LDB_H(bB, Bs[1][1]);
    stage_half<ALD>(Ae + 128*ALD, As[0][1], t);
    stage_half<1024>(Be + 128*1024, Bs[0][1], t);
    SCHED0;
    LGKM4;
    PRIO(1); MFMA_G(0, afA, bA, 0);
    LGKM0;
    MFMA_G(0, afA, bB, 2); PRIO(0);
    VMC(4); BAR();

    // mph4: c1 M-half1 | stage o h0 pair (slots read mph3)
    LDA_H(afA, As[1][1]);
    stage_half<ALD>(Ao, As[1][0], t);
    stage_half<1024>(Bo, Bs[1][0], t);
    SCHED0;
    LGKM0;
    PRIO(1); MFMA_G(1, afA, bA, 0); MFMA_G(1, afA, bB, 2); PRIO(0);
    VMC(4); BAR();

    if ((i & 7) == 7) epilogue(i >> 3);
  }
  VMC(0);   // drain DMA before wave exit
}

// Distinct names so rocprof separates the two GEMMs.
__global__ __launch_bounds__(512, 2) void gemm_qkv(
    const u16* __restrict__ A, const u16* __restrict__ Bm,
    void* __restrict__ C, const float* __restrict__ aux) {
  gemm_body<3072, 0, 1024, 3, 0>(A, Bm, C, aux);
}
__global__ __launch_bounds__(512, 2) void gemm_out(
    const u16* __restrict__ A, const u16* __restrict__ Bm,
    void* __restrict__ C, const float* __restrict__ aux) {
  gemm_body<1024, 1, 1024, 1, 1>(A, Bm, C, aux);
}

// kv[bh][d][e] = sum_n K[n][d] * V[n][e];  ksum[bh][d] = sum_n K[n][d]
// 64-token tiles (8 iterations, half the barriers of the 32-token version).
__global__ __launch_bounds__(256) void kv_kernel(const u16* __restrict__ QKV,
    float* __restrict__ kvws, float* __restrict__ ksws) {
  __shared__ u16 Kl[64 * 64];
  __shared__ u16 Vl[64 * 64];
  const int t = threadIdx.x;
  const int l = t & 63, w = t >> 6;
  const int rl = l & 15, kg = l >> 4;
  const int bid = blockIdx.x;
  const int bh = bid >> 3, ns = bid & 7;
  const int b = bh >> 4, h = bh & 15;
  const long tok0 = (long)b * 4096 + ns * 512;

  f32x4 acc[4];
  #pragma unroll
  for (int i = 0; i < 4; ++i) acc[i] = (f32x4){0.f, 0.f, 0.f, 0.f};
  float ks = 0.f;

  for (int it = 0; it < 8; ++it) {
    const long tb = tok0 + it * 64;
    #pragma unroll
    for (int c = 0; c < 2; ++c) {
      const int ch = c * 256 + t;        // 0..511 chunks of 16B
      const int srow = ch >> 3, scc = ch & 7;
      g2l16(QKV + (tb + srow) * QKVN + 1024 + h * 64 + scc * 8, (char*)Kl + ch * 16);
      g2l16(QKV + (tb + srow) * QKVN + 2048 + h * 64 + scc * 8, (char*)Vl + ch * 16);
    }
    __syncthreads();
    union { u16x8 u; bf16x8 v; } au, bu;
    #pragma unroll
    for (int ksb = 0; ksb < 2; ++ksb) {       // two 32-token sub-tiles
      #pragma unroll
      for (int j = 0; j < 8; ++j) au.u[j] = Kl[(ksb * 32 + kg * 8 + j) * 64 + w * 16 + rl];
      #pragma unroll
      for (int ni = 0; ni < 4; ++ni) {
        #pragma unroll
        for (int j = 0; j < 8; ++j) bu.u[j] = Vl[(ksb * 32 + kg * 8 + j) * 64 + ni * 16 + rl];
        acc[ni] = __builtin_amdgcn_mfma_f32_16x16x32_bf16(au.v, bu.v, acc[ni], 0, 0, 0);
      }
    }
    #pragma unroll
    for (int r = 0; r < 16; ++r) ks += bf2f(Kl[(w * 16 + r) * 64 + (t & 63)]);
    __syncthreads();
  }
  float* kvb = kvws + bh * 4096;
  #pragma unroll
  for (int ni = 0; ni < 4; ++ni)
    #pragma unroll
    for (int j = 0; j < 4; ++j) {
      const int d = w * 16 + kg * 4 + j;
      const int e = ni * 16 + rl;
      atomicAdd(&kvb[d * 64 + e], acc[ni][j]);
    }
  atomicAdd(&ksws[bh * 64 + (t & 63)], ks);
}

// Per-head normalize Q -> compact Qc (ld 1024):
// Qc[n][h*64+d] = Q[n][h*64+d] / (sum_d' Q[n][h*64+d'] * ksum[b*16+h][d'] + 1e-6)
__global__ __launch_bounds__(256) void scale_q(const u16* __restrict__ QKV,
    const float* __restrict__ ksws, u16* __restrict__ Qc) {
  __shared__ float ksl[1024];
  const int bid = blockIdx.x, t = threadIdx.x;
  const int n0 = bid * 16;
  const int b = n0 >> 12;
  #pragma unroll
  for (int i = 0; i < 4; ++i) ksl[i * 256 + t] = ksws[b * 1024 + i * 256 + t];
  __syncthreads();
  const int h = t & 15, ti = t >> 4;
  const u16* qp = QKV + (long)(n0 + ti) * QKVN + h * 64;
  u16* op = Qc + (long)(n0 + ti) * 1024 + h * 64;
  u16x8 v[8];
  float norm = 1e-6f;
  #pragma unroll
  for (int i = 0; i < 8; ++i) {
    v[i] = *(const u16x8*)(qp + i * 8);
    #pragma unroll
    for (int j = 0; j < 8; ++j) norm += bf2f(v[i][j]) * ksl[h * 64 + i * 8 + j];
  }
  const float inv = 1.0f / norm;
  #pragma unroll
  for (int i = 0; i < 8; ++i) {
    u16x8 o;
    #pragma unroll
    for (int j = 0; j < 8; ++j) o[j] = f2bf(bf2f(v[i][j]) * inv);
    *(u16x8*)(op + i * 8) = o;
  }
}

// W2T[b][o][h*64+d] = sum_e kv[b*16+h][d][e] * Wo[h*64+e][o]  (Wo fp32 direct)
__global__ __launch_bounds__(256) void w2_kernel(const float* __restrict__ kvws,
    const float* __restrict__ Wo, u16* __restrict__ W2T) {
  __shared__ float kvl[64][64];
  const int bid = blockIdx.x, t = threadIdx.x;
  const int bh = bid >> 2, os = bid & 3;
  const int b = bh >> 4, h = bh & 15;
  const float* kvb = kvws + bh * 4096;
  #pragma unroll
  for (int i = 0; i < 16; ++i) ((float*)kvl)[i * 256 + t] = kvb[i * 256 + t];
  __syncthreads();
  const int o = os * 256 + t;
  float wo[64];
  #pragma unroll
  for (int e = 0; e < 64; ++e) wo[e] = Wo[(long)(h * 64 + e) * 1024 + o];
  u16* out = W2T + (long)b * 1048576 + (long)o * 1024 + h * 64;
  for (int d = 0; d < 64; ++d) {
    float s = 0.f;
    #pragma unroll
    for (int e = 0; e < 64; ++e) s += wo[e] * kvl[d][e];
    out[d] = f2bf(s);
  }
}

// Merged weight prep. Blocks 0..255: WqkvT rows 0..2047 = (W{q,k}@blockdiag(proj))^T.
// Blocks 256..511: WqkvT rows 2048..3071 = Wv^T (64x64 tiled transpose).
__global__ __launch_bounds__(256) void prep_w(const float* __restrict__ Wq,
    const float* __restrict__ Wk, const float* __restrict__ proj,
    const float* __restrict__ Wv, u16* __restrict__ WqkvT) {
  __shared__ float Wl[128][65];
  __shared__ float Pl[64][65];
  const int t = threadIdx.x;
  if (blockIdx.x < 256) {
    const int bid = blockIdx.x;
    const int m = bid >> 7, h = (bid >> 3) & 15, cb = bid & 7;
    const float* W = m ? Wk : Wq;
    #pragma unroll
    for (int i = 0; i < 16; ++i) {
      const int idx = i * 256 + t;
      Pl[idx >> 6][idx & 63] = proj[idx];
    }
    #pragma unroll
    for (int i = 0; i < 32; ++i) {
      const int idx = i * 256 + t;
      const int c = idx >> 6, d = idx & 63;
      Wl[c][d] = W[(long)(cb * 128 + c) * 1024 + h * 64 + d];
    }
    __syncthreads();
    const int c = t & 127, j0 = (t >> 7) * 32;
    float a[32];
    #pragma unroll
    for (int jj = 0; jj < 32; ++jj) a[jj] = 0.f;
    for (int d = 0; d < 64; ++d) {
      const float wv = Wl[c][d];
      #pragma unroll
      for (int jj = 0; jj < 32; ++jj) a[jj] += wv * Pl[d][j0 + jj];
    }
    #pragma unroll
    for (int jj = 0; jj < 32; ++jj)
      WqkvT[(long)(m * 1024 + h * 64 + j0 + jj) * 1024 + cb * 128 + c] = f2bf(a[jj]);
  } else {
    const int bid = blockIdx.x - 256;
    const int rt = (bid >> 4) & 15, ct = bid & 15;
    const int j = t & 63;
    #pragma unroll
    for (int p = 0; p < 16; ++p) {
      const int i = p * 4 + (t >> 6);
      Pl[0][0] = Pl[0][0];  // no-op
      Wl[0][i * 0] = Wl[0][0];
      ((float*)Pl)[0] = ((float*)Pl)[0];
      (void)0;
      // use Wl as the transpose tile (64x65 sub-region)
      Wl[i][j] = Wv[(long)(rt * 64 + i) * 1024 + ct * 64 + j];
    }
    __syncthreads();
    u16* dst = WqkvT + (long)2048 * 1024;
    #pragma unroll
    for (int p = 0; p < 16; ++p) {
      const int i = p * 4 + (t >> 6);
      dst[(long)(ct * 64 + i) * 1024 + rt * 64 + j] = f2bf(Wl[j][i]);
    }
  }
}

__global__ __launch_bounds__(256) void conv_x(const float* __restrict__ x,
                                              u16* __restrict__ xb) {
  const int idx = blockIdx.x * 256 + threadIdx.x;
  const float4* p = (const float4*)x + (long)idx * 2;
  const float4 a = p[0], b = p[1];
  u16x8 o;
  o[0] = f2bf(a.x); o[1] = f2bf(a.y); o[2] = f2bf(a.z); o[3] = f2bf(a.w);
  o[4] = f2bf(b.x); o[5] = f2bf(b.y); o[6] = f2bf(b.z); o[7] = f2bf(b.w);
  *((u16x8*)xb + idx) = o;
}

extern "C" void kernel_launch(void* const* d_in, const int* in_sizes, int n_in,
                              void* d_out, int out_size, void* d_ws, size_t ws_size,
                              hipStream_t stream) {
  const float* x    = (const float*)d_in[0];
  const float* mask = (const float*)d_in[1];
  const float* Wq   = (const float*)d_in[2];
  const float* Wk   = (const float*)d_in[3];
  const float* Wv   = (const float*)d_in[4];
  const float* Wo   = (const float*)d_in[5];
  const float* proj = (const float*)d_in[6];

  char* ws = (char*)d_ws;
  u16*  WqkvT = (u16*)(ws);                    // 3072x1024 bf16 = 6 MB
  u16*  xb    = (u16*)(ws + 8388608);          // 16384x1024 bf16 = 32 MB
  u16*  QKV   = (u16*)(ws + 41943040);         // 16384x3072 bf16 = 96 MB
  float* kvws = (float*)(ws + 142606336);      // 64*64*64 f32 = 1 MB
  float* ksws = (float*)(ws + 143654912);      // 64*64 f32 = 16 KB
  // Dead-region reuse (stream-ordered, race-free):
  u16*  Qc   = xb;                             // xb dead after QKV GEMM
  u16*  W2T  = (u16*)(ws);                     // WqkvT dead after QKV GEMM (8 MB)
  if (ws_size < (size_t)143671296) return;

  hipMemsetAsync(kvws, 0, 1064960, stream);
  prep_w<<<512, 256, 0, stream>>>(Wq, Wk, proj, Wv, WqkvT);
  conv_x<<<8192, 256, 0, stream>>>(x, xb);
  gemm_qkv<<<256, 512, 0, stream>>>(xb, WqkvT, (void*)QKV, mask);
  kv_kernel<<<512, 256, 0, stream>>>(QKV, kvws, ksws);
  scale_q<<<1024, 256, 0, stream>>>(QKV, ksws, Qc);
  w2_kernel<<<256, 256, 0, stream>>>(kvws, Wo, W2T);
  gemm_out<<<256, 512, 0, stream>>>(Qc, W2T, d_out, nullptr);
}

// Round 11
// 240.599 us; speedup vs baseline: 1.1657x; 1.1657x over previous
//
#include <hip/hip_runtime.h>
#include <stdint.h>

#define TOKENS 16384
#define KDIM 1024
#define QKVN 3072

typedef unsigned short u16;
using bf16x8 = __attribute__((ext_vector_type(8))) __bf16;
using f32x4  = __attribute__((ext_vector_type(4))) float;
using u16x8  = __attribute__((ext_vector_type(8))) unsigned short;

__device__ inline u16 f2bf(float f) {
  union { float f; uint32_t u; } v; v.f = f;
  uint32_t u = v.u;
  return (u16)((u + 0x7FFFu + ((u >> 16) & 1u)) >> 16);
}
__device__ inline float bf2f(u16 s) {
  union { uint32_t u; float f; } v; v.u = ((uint32_t)s) << 16;
  return v.f;
}
__device__ inline void g2l16(const void* g, void* l) {
  __builtin_amdgcn_global_load_lds(
      (const __attribute__((address_space(1))) void*)g,
      (__attribute__((address_space(3))) void*)l, 16, 0, 0);
}

// Stage one 128x64 bf16 half-tile (16 KB): 512 threads x 2 global_load_lds x 16B.
// Linear LDS dest; global source pre-swizzled so swizzled ds_reads are conflict-free.
template<int LD>
__device__ inline void stage_half(const u16* __restrict__ g, u16* l, int t) {
  #pragma unroll
  for (int i = 0; i < 2; ++i) {
    const int ch = i * 512 + t;          // 0..1023 chunks of 16B
    const int row = ch >> 3;             // 0..127
    const int cc = (ch & 7) ^ (row & 7); // source chunk pre-swizzle
    g2l16(g + (long)row * LD + cc * 8, (char*)l + ch * 16);
  }
}

// Fragment loads from a 128x64 half (16 KB); XOR-swizzled ds_read_b128.
#define LDA_H(DST, BASE) do { \
  _Pragma("unroll") \
  for (int mi = 0; mi < 4; ++mi) { \
    const int row = wm*64 + mi*16 + rl; \
    const char* p = (const char*)(BASE) + row*128; \
    const int sw = (row & 7) << 4; \
    DST[mi][0] = *(const bf16x8*)(p + ((kg*16) ^ sw)); \
    DST[mi][1] = *(const bf16x8*)(p + ((64 + kg*16) ^ sw)); \
  } \
} while (0)

#define LDB_H(DST, BASE) do { \
  _Pragma("unroll") \
  for (int ni = 0; ni < 2; ++ni) { \
    const int row = wn*32 + ni*16 + rl; \
    const char* p = (const char*)(BASE) + row*128; \
    const int sw = (row & 7) << 4; \
    DST[ni][0] = *(const bf16x8*)(p + ((kg*16) ^ sw)); \
    DST[ni][1] = *(const bf16x8*)(p + ((64 + kg*16) ^ sw)); \
  } \
} while (0)

// 32-MFMA merged burst: both N-halves of one M-half; 16 independent acc chains.
#define MFMA2Q(MH, AV, BV0, BV1) do { \
  __builtin_amdgcn_s_setprio(1); \
  _Pragma("unroll") \
  for (int kh = 0; kh < 2; ++kh) \
    _Pragma("unroll") \
    for (int mi = 0; mi < 4; ++mi) \
      _Pragma("unroll") \
      for (int ni = 0; ni < 2; ++ni) { \
        acc[(MH)*4+mi][ni]   = __builtin_amdgcn_mfma_f32_16x16x32_bf16( \
            AV[mi][kh], BV0[ni][kh], acc[(MH)*4+mi][ni], 0, 0, 0); \
        acc[(MH)*4+mi][2+ni] = __builtin_amdgcn_mfma_f32_16x16x32_bf16( \
            AV[mi][kh], BV1[ni][kh], acc[(MH)*4+mi][2+ni], 0, 0, 0); \
      } \
  __builtin_amdgcn_s_setprio(0); \
} while (0)

#define LGKM0 do { \
  asm volatile("s_waitcnt lgkmcnt(0)" ::: "memory"); \
  __builtin_amdgcn_sched_barrier(0); \
} while (0)
#define VMC(N) asm volatile("s_waitcnt vmcnt(" #N ")" ::: "memory")
#define BAR() __builtin_amdgcn_s_barrier()

// C = A(16384 x 1024 bf16, ld ALD) @ B^T (B stored N x 1024 bf16 rm).
// 256x256 tile, 8 waves (2Mx4N). 4 merged phases / 2-K-chunk iteration, ONE
// barrier per phase: {reads; stage; lgkm0; MFMA x32; [vmcnt]; BAR}.
// vmcnt(4) at mph2/mph4 ONLY (m201 discipline). Hazard proof (re-derived):
//  - reader waves drain own ds_reads (lgkm0) BEFORE the barrier, so DMA issued
//    in phase p (after BAR(p-1)) can never race reads completed before it;
//  - drain table: mph1+prev-mph4 stages drain at mph2's vmcnt(4) (12 out-
//    standing -> 4), read at mph3/next-mph3; mph2+mph3 stages drain at mph4's
//    vmcnt(4), read next-iter mph1/mph2. Every slot lands >=1 barrier before
//    its first read. Prologue pair drains at iter0's mph2, read at mph3.
// EPI 0: QKV epilogue (phi cols<2048, mask on K cols), bf16 C (ld 3072), aux=mask
// EPI 1: plain fp32 C (ld NTOT)
template<int NTOT, int EPI, int ALD, int NT, int PERB>
__device__ __forceinline__ void gemm_body(
    const u16* __restrict__ A, const u16* __restrict__ Bm,
    void* __restrict__ C, const float* __restrict__ aux) {
  __shared__ u16 As[2][2][8192];   // [kchunk parity][row-half][128 x 64]
  __shared__ u16 Bs[2][2][8192];
  const int t = threadIdx.x;
  const int l = t & 63;
  const int w = t >> 6;
  const int rl = l & 15, kg = l >> 4;
  const int wm = w >> 2, wn = w & 3;      // 2M x 4N waves
  constexpr int nbn = NTOT / 256;
  constexpr int nwg = 64 * nbn;           // total output tiles
  constexpr int GRID = nwg / NT;          // blocks launched
  constexpr int KC = NT * 16;             // K-chunks (64 wide) per block
  constexpr int IT = KC / 2;              // iterations (2 chunks each)
  static_assert(nwg % 8 == 0, "bijective xcd swizzle");
  const int bid = blockIdx.x;

  auto tcoord = [&](int ot, long& tar, long& tbr) {
    const int gt = ot * GRID + bid;
    const int swz = (gt & 7) * (nwg / 8) + (gt >> 3);
    tar = (long)(swz / nbn) * 256;
    tbr = (long)(swz % nbn) * 256;
  };
  auto asrc = [&](int ch) {
    long ta, tb; tcoord(ch >> 4, ta, tb);
    return A + ta * ALD + (ch & 15) * 64;
  };
  auto bsrc = [&](int ch) {
    long ta, tb; tcoord(ch >> 4, ta, tb);
    return Bm + (PERB ? (ta >> 12) * 1048576 : 0) + tb * 1024 + (ch & 15) * 64;
  };

  f32x4 acc[8][4];
  #pragma unroll
  for (int i = 0; i < 8; ++i)
    #pragma unroll
    for (int j = 0; j < 4; ++j)
      acc[i][j] = (f32x4){0.f, 0.f, 0.f, 0.f};

  bf16x8 afA[4][2], bA[2][2], bB[2][2];

  auto epilogue = [&](int ot) {
    long ar0, br0; tcoord(ot, ar0, br0);
    #pragma unroll
    for (int mh = 0; mh < 2; ++mh)
      #pragma unroll
      for (int mi = 0; mi < 4; ++mi)
        #pragma unroll
        for (int j = 0; j < 4; ++j) {
          const long row = ar0 + mh*128 + wm*64 + mi*16 + kg*4 + j;
          float rs = 0.f;
          if (EPI == 0) rs = aux[row];            // mask[token]
          #pragma unroll
          for (int nh = 0; nh < 2; ++nh)
            #pragma unroll
            for (int ni = 0; ni < 2; ++ni) {
              const long col = br0 + nh*128 + wn*32 + ni*16 + rl;
              float v = acc[mh*4+mi][nh*2+ni][j];
              if (EPI == 0) {
                if (col < 2048) {                  // Q or K: phi = elu(x)+1
                  v = (v > 0.f) ? (v + 1.f) : __expf(v);
                  if (col >= 1024) v *= rs;        // K: * mask[token]
                }
                ((u16*)C)[row * QKVN + col] = f2bf(v);
              } else {
                ((float*)C)[row * NTOT + col] = v;
              }
            }
        }
    #pragma unroll
    for (int i = 0; i < 8; ++i)
      #pragma unroll
      for (int j = 0; j < 4; ++j)
        acc[i][j] = (f32x4){0.f, 0.f, 0.f, 0.f};
  };

  // Prologue: chunk0 all 4 halves + chunk1 h0 pair (h1 pair staged at mph1).
  {
    const u16* A0s = asrc(0); const u16* B0s = bsrc(0);
    const u16* A1s = asrc(1); const u16* B1s = bsrc(1);
    stage_half<ALD >(A0s,             As[0][0], t);
    stage_half<1024>(B0s,             Bs[0][0], t);
    stage_half<1024>(B0s + 128*1024,  Bs[0][1], t);
    stage_half<ALD >(A0s + 128*ALD,   As[0][1], t);
    stage_half<ALD >(A1s,             As[1][0], t);
    stage_half<1024>(B1s,             Bs[1][0], t);
    VMC(4);            // chunk0's 4 halves landed; chunk1 h0 pair in flight
    BAR();
  }

  for (int i = 0; i < IT; ++i) {
    const int o1 = 2*i + 1;
    const int e = (2*i + 2 < KC) ? 2*i + 2 : KC - 1;   // parity 0
    const int o = (2*i + 3 < KC) ? 2*i + 3 : KC - 1;   // parity 1
    const u16* Ao1 = asrc(o1); const u16* Bo1 = bsrc(o1);
    const u16* Ae = asrc(e);   const u16* Be = bsrc(e);
    const u16* Ao = asrc(o);   const u16* Bo = bsrc(o);

    // mph1: c0 M-half0 | stage c1 h1 pair (slots read prev-iter mph3/mph4)
    LDA_H(afA, As[0][0]); LDB_H(bA, Bs[0][0]); LDB_H(bB, Bs[0][1]);
    stage_half<ALD>(Ao1 + 128*ALD, As[1][1], t);
    stage_half<1024>(Bo1 + 128*1024, Bs[1][1], t);
    LGKM0;
    MFMA2Q(0, afA, bA, bB);
    BAR();                                   // no vmcnt here (drains at mph2)

    // mph2: c0 M-half1 | stage e h0 pair (slots read mph1)
    LDA_H(afA, As[0][1]);
    stage_half<ALD>(Ae, As[0][0], t);
    stage_half<1024>(Be, Bs[0][0], t);
    LGKM0;
    MFMA2Q(1, afA, bA, bB);
    VMC(4); BAR();                           // drains mph1 + prev-mph4 stages

    // mph3: c1 M-half0 | stage e h1 pair (As[0][1] read mph2, Bs[0][1] read mph1)
    LDA_H(afA, As[1][0]); LDB_H(bA, Bs[1][0]); LDB_H(bB, Bs[1][1]);
    stage_half<ALD>(Ae + 128*ALD, As[0][1], t);
    stage_half<1024>(Be + 128*1024, Bs[0][1], t);
    LGKM0;
    MFMA2Q(0, afA, bA, bB);
    BAR();                                   // no vmcnt here (drains at mph4)

    // mph4: c1 M-half1 | stage o h0 pair (slots read mph3)
    LDA_H(afA, As[1][1]);
    stage_half<ALD>(Ao, As[1][0], t);
    stage_half<1024>(Bo, Bs[1][0], t);
    LGKM0;
    MFMA2Q(1, afA, bA, bB);
    VMC(4); BAR();                           // drains mph2 + mph3 stages

    if ((i & 7) == 7) epilogue(i >> 3);
  }
  VMC(0);   // drain DMA before wave exit
}

// Distinct names so rocprof separates the two GEMMs.
__global__ __launch_bounds__(512, 2) void gemm_qkv(
    const u16* __restrict__ A, const u16* __restrict__ Bm,
    void* __restrict__ C, const float* __restrict__ aux) {
  gemm_body<3072, 0, 1024, 3, 0>(A, Bm, C, aux);
}
__global__ __launch_bounds__(512, 2) void gemm_out(
    const u16* __restrict__ A, const u16* __restrict__ Bm,
    void* __restrict__ C, const float* __restrict__ aux) {
  gemm_body<1024, 1, 1024, 1, 1>(A, Bm, C, aux);
}

// kv[bh][d][e] = sum_n K[n][d] * V[n][e];  ksum[bh][d] = sum_n K[n][d]
__global__ __launch_bounds__(256) void kv_kernel(const u16* __restrict__ QKV,
    float* __restrict__ kvws, float* __restrict__ ksws) {
  __shared__ u16 Kl[32 * 64];
  __shared__ u16 Vl[32 * 64];
  const int t = threadIdx.x;
  const int l = t & 63, w = t >> 6;
  const int rl = l & 15, kg = l >> 4;
  const int bid = blockIdx.x;
  const int bh = bid >> 3, ns = bid & 7;
  const int b = bh >> 4, h = bh & 15;
  const long tok0 = (long)b * 4096 + ns * 512;

  f32x4 acc[4];
  #pragma unroll
  for (int i = 0; i < 4; ++i) acc[i] = (f32x4){0.f, 0.f, 0.f, 0.f};
  float ks = 0.f;
  const int srow = t >> 3, scc = t & 7;

  for (int it = 0; it < 16; ++it) {
    const long tb = tok0 + it * 32;
    g2l16(QKV + (tb + srow) * QKVN + 1024 + h * 64 + scc * 8, (char*)Kl + t * 16);
    g2l16(QKV + (tb + srow) * QKVN + 2048 + h * 64 + scc * 8, (char*)Vl + t * 16);
    __syncthreads();
    union { u16x8 u; bf16x8 v; } au, bu;
    #pragma unroll
    for (int j = 0; j < 8; ++j) au.u[j] = Kl[(kg * 8 + j) * 64 + w * 16 + rl];
    #pragma unroll
    for (int ni = 0; ni < 4; ++ni) {
      #pragma unroll
      for (int j = 0; j < 8; ++j) bu.u[j] = Vl[(kg * 8 + j) * 64 + ni * 16 + rl];
      acc[ni] = __builtin_amdgcn_mfma_f32_16x16x32_bf16(au.v, bu.v, acc[ni], 0, 0, 0);
    }
    #pragma unroll
    for (int r = 0; r < 8; ++r) ks += bf2f(Kl[(w * 8 + r) * 64 + (t & 63)]);
    __syncthreads();
  }
  float* kvb = kvws + bh * 4096;
  #pragma unroll
  for (int ni = 0; ni < 4; ++ni)
    #pragma unroll
    for (int j = 0; j < 4; ++j) {
      const int d = w * 16 + kg * 4 + j;
      const int e = ni * 16 + rl;
      atomicAdd(&kvb[d * 64 + e], acc[ni][j]);
    }
  atomicAdd(&ksws[bh * 64 + (t & 63)], ks);
}

// Merged post-kv small work. Blocks 0..1023: per-head normalize Q -> compact
// Qc (ld 1024). Blocks 1024..1279: W2T[b][o][hd] = sum_e kv[bh][d][e]*Wo[he][o].
__global__ __launch_bounds__(256) void finish_kernel(const u16* __restrict__ QKV,
    const float* __restrict__ ksws, const float* __restrict__ kvws,
    const float* __restrict__ Wo, u16* __restrict__ Qc, u16* __restrict__ W2T) {
  __shared__ float sh[4096];
  const int t = threadIdx.x;
  if (blockIdx.x < 1024) {
    const int bid = blockIdx.x;
    const int n0 = bid * 16;
    const int b = n0 >> 12;
    #pragma unroll
    for (int i = 0; i < 4; ++i) sh[i * 256 + t] = ksws[b * 1024 + i * 256 + t];
    __syncthreads();
    const int h = t & 15, ti = t >> 4;
    const u16* qp = QKV + (long)(n0 + ti) * QKVN + h * 64;
    u16* op = Qc + (long)(n0 + ti) * 1024 + h * 64;
    u16x8 v[8];
    float norm = 1e-6f;
    #pragma unroll
    for (int i = 0; i < 8; ++i) {
      v[i] = *(const u16x8*)(qp + i * 8);
      #pragma unroll
      for (int j = 0; j < 8; ++j) norm += bf2f(v[i][j]) * sh[h * 64 + i * 8 + j];
    }
    const float inv = 1.0f / norm;
    #pragma unroll
    for (int i = 0; i < 8; ++i) {
      u16x8 o;
      #pragma unroll
      for (int j = 0; j < 8; ++j) o[j] = f2bf(bf2f(v[i][j]) * inv);
      *(u16x8*)(op + i * 8) = o;
    }
  } else {
    const int bid = blockIdx.x - 1024;
    const int bh = bid >> 2, os = bid & 3;
    const int b = bh >> 4, h = bh & 15;
    const float* kvb = kvws + bh * 4096;
    #pragma unroll
    for (int i = 0; i < 16; ++i) sh[i * 256 + t] = kvb[i * 256 + t];
    __syncthreads();
    const int o = os * 256 + t;
    float wo[64];
    #pragma unroll
    for (int e = 0; e < 64; ++e) wo[e] = Wo[(long)(h * 64 + e) * 1024 + o];
    u16* out = W2T + (long)b * 1048576 + (long)o * 1024 + h * 64;
    for (int d = 0; d < 64; ++d) {
      float s = 0.f;
      #pragma unroll
      for (int e = 0; e < 64; ++e) s += wo[e] * sh[d * 64 + e];
      out[d] = f2bf(s);
    }
  }
}

// Merged weight prep. Blocks 0..255: WqkvT rows 0..2047 = (W{q,k}@blockdiag(proj))^T.
// Blocks 256..511: WqkvT rows 2048..3071 = Wv^T (64x64 tiled transpose).
__global__ __launch_bounds__(256) void prep_w(const float* __restrict__ Wq,
    const float* __restrict__ Wk, const float* __restrict__ proj,
    const float* __restrict__ Wv, u16* __restrict__ WqkvT) {
  __shared__ float Wl[128][65];
  __shared__ float Pl[64][65];
  const int t = threadIdx.x;
  if (blockIdx.x < 256) {
    const int bid = blockIdx.x;
    const int m = bid >> 7, h = (bid >> 3) & 15, cb = bid & 7;
    const float* W = m ? Wk : Wq;
    #pragma unroll
    for (int i = 0; i < 16; ++i) {
      const int idx = i * 256 + t;
      Pl[idx >> 6][idx & 63] = proj[idx];
    }
    #pragma unroll
    for (int i = 0; i < 32; ++i) {
      const int idx = i * 256 + t;
      const int c = idx >> 6, d = idx & 63;
      Wl[c][d] = W[(long)(cb * 128 + c) * 1024 + h * 64 + d];
    }
    __syncthreads();
    const int c = t & 127, j0 = (t >> 7) * 32;
    float a[32];
    #pragma unroll
    for (int jj = 0; jj < 32; ++jj) a[jj] = 0.f;
    for (int d = 0; d < 64; ++d) {
      const float wv = Wl[c][d];
      #pragma unroll
      for (int jj = 0; jj < 32; ++jj) a[jj] += wv * Pl[d][j0 + jj];
    }
    #pragma unroll
    for (int jj = 0; jj < 32; ++jj)
      WqkvT[(long)(m * 1024 + h * 64 + j0 + jj) * 1024 + cb * 128 + c] = f2bf(a[jj]);
  } else {
    const int bid = blockIdx.x - 256;
    const int rt = (bid >> 4) & 15, ct = bid & 15;
    const int j = t & 63;
    #pragma unroll
    for (int p = 0; p < 16; ++p) {
      const int i = p * 4 + (t >> 6);
      Wl[i][j] = Wv[(long)(rt * 64 + i) * 1024 + ct * 64 + j];
    }
    __syncthreads();
    u16* dst = WqkvT + (long)2048 * 1024;
    #pragma unroll
    for (int p = 0; p < 16; ++p) {
      const int i = p * 4 + (t >> 6);
      dst[(long)(ct * 64 + i) * 1024 + rt * 64 + j] = f2bf(Wl[j][i]);
    }
  }
}

__global__ __launch_bounds__(256) void conv_x(const float* __restrict__ x,
                                              u16* __restrict__ xb) {
  const int idx = blockIdx.x * 256 + threadIdx.x;
  const float4* p = (const float4*)x + (long)idx * 2;
  const float4 a = p[0], b = p[1];
  u16x8 o;
  o[0] = f2bf(a.x); o[1] = f2bf(a.y); o[2] = f2bf(a.z); o[3] = f2bf(a.w);
  o[4] = f2bf(b.x); o[5] = f2bf(b.y); o[6] = f2bf(b.z); o[7] = f2bf(b.w);
  *((u16x8*)xb + idx) = o;
}

extern "C" void kernel_launch(void* const* d_in, const int* in_sizes, int n_in,
                              void* d_out, int out_size, void* d_ws, size_t ws_size,
                              hipStream_t stream) {
  const float* x    = (const float*)d_in[0];
  const float* mask = (const float*)d_in[1];
  const float* Wq   = (const float*)d_in[2];
  const float* Wk   = (const float*)d_in[3];
  const float* Wv   = (const float*)d_in[4];
  const float* Wo   = (const float*)d_in[5];
  const float* proj = (const float*)d_in[6];

  char* ws = (char*)d_ws;
  u16*  WqkvT = (u16*)(ws);                    // 3072x1024 bf16 = 6 MB
  u16*  xb    = (u16*)(ws + 8388608);          // 16384x1024 bf16 = 32 MB
  u16*  QKV   = (u16*)(ws + 41943040);         // 16384x3072 bf16 = 96 MB
  float* kvws = (float*)(ws + 142606336);      // 64*64*64 f32 = 1 MB
  float* ksws = (float*)(ws + 143654912);      // 64*64 f32 = 16 KB
  // Dead-region reuse (stream-ordered, race-free):
  u16*  Qc   = xb;                             // xb dead after QKV GEMM
  u16*  W2T  = (u16*)(ws);                     // WqkvT dead after QKV GEMM (8 MB)
  if (ws_size < (size_t)143671296) return;

  hipMemsetAsync(kvws, 0, 1064960, stream);
  prep_w<<<512, 256, 0, stream>>>(Wq, Wk, proj, Wv, WqkvT);
  conv_x<<<8192, 256, 0, stream>>>(x, xb);
  gemm_qkv<<<256, 512, 0, stream>>>(xb, WqkvT, (void*)QKV, mask);
  kv_kernel<<<512, 256, 0, stream>>>(QKV, kvws, ksws);
  finish_kernel<<<1280, 256, 0, stream>>>(QKV, ksws, kvws, Wo, Qc, W2T);
  gemm_out<<<256, 512, 0, stream>>>(Qc, W2T, d_out, nullptr);
}

// Round 12
// 234.898 us; speedup vs baseline: 1.1939x; 1.0243x over previous
//
#include <hip/hip_runtime.h>
#include <stdint.h>

#define TOKENS 16384
#define KDIM 1024
#define QKVN 3072

typedef unsigned short u16;
using bf16x8 = __attribute__((ext_vector_type(8))) __bf16;
using f32x4  = __attribute__((ext_vector_type(4))) float;
using u16x8  = __attribute__((ext_vector_type(8))) unsigned short;

__device__ inline u16 f2bf(float f) {
  union { float f; uint32_t u; } v; v.f = f;
  uint32_t u = v.u;
  return (u16)((u + 0x7FFFu + ((u >> 16) & 1u)) >> 16);
}
__device__ inline float bf2f(u16 s) {
  union { uint32_t u; float f; } v; v.u = ((uint32_t)s) << 16;
  return v.f;
}
__device__ inline void g2l16(const void* g, void* l) {
  __builtin_amdgcn_global_load_lds(
      (const __attribute__((address_space(1))) void*)g,
      (__attribute__((address_space(3))) void*)l, 16, 0, 0);
}

// Stage one 128x64 bf16 half-tile (16 KB): 512 threads x 2 global_load_lds x 16B.
// Linear LDS dest; global source pre-swizzled so swizzled ds_reads are conflict-free.
template<int LD>
__device__ inline void stage_half(const u16* __restrict__ g, u16* l, int t) {
  #pragma unroll
  for (int i = 0; i < 2; ++i) {
    const int ch = i * 512 + t;          // 0..1023 chunks of 16B
    const int row = ch >> 3;             // 0..127
    const int cc = (ch & 7) ^ (row & 7); // source chunk pre-swizzle
    g2l16(g + (long)row * LD + cc * 8, (char*)l + ch * 16);
  }
}

// Fragment loads from a 128x64 half (16 KB); XOR-swizzled ds_read_b128.
#define LDA_H(DST, BASE) do { \
  _Pragma("unroll") \
  for (int mi = 0; mi < 4; ++mi) { \
    const int row = wm*64 + mi*16 + rl; \
    const char* p = (const char*)(BASE) + row*128; \
    const int sw = (row & 7) << 4; \
    DST[mi][0] = *(const bf16x8*)(p + ((kg*16) ^ sw)); \
    DST[mi][1] = *(const bf16x8*)(p + ((64 + kg*16) ^ sw)); \
  } \
} while (0)

#define LDB_H(DST, BASE) do { \
  _Pragma("unroll") \
  for (int ni = 0; ni < 2; ++ni) { \
    const int row = wn*32 + ni*16 + rl; \
    const char* p = (const char*)(BASE) + row*128; \
    const int sw = (row & 7) << 4; \
    DST[ni][0] = *(const bf16x8*)(p + ((kg*16) ^ sw)); \
    DST[ni][1] = *(const bf16x8*)(p + ((64 + kg*16) ^ sw)); \
  } \
} while (0)

// 32-MFMA merged burst: both N-halves of one M-half; 16 independent acc chains.
#define MFMA2Q(MH, AV, BV0, BV1) do { \
  __builtin_amdgcn_s_setprio(1); \
  _Pragma("unroll") \
  for (int kh = 0; kh < 2; ++kh) \
    _Pragma("unroll") \
    for (int mi = 0; mi < 4; ++mi) \
      _Pragma("unroll") \
      for (int ni = 0; ni < 2; ++ni) { \
        acc[(MH)*4+mi][ni]   = __builtin_amdgcn_mfma_f32_16x16x32_bf16( \
            AV[mi][kh], BV0[ni][kh], acc[(MH)*4+mi][ni], 0, 0, 0); \
        acc[(MH)*4+mi][2+ni] = __builtin_amdgcn_mfma_f32_16x16x32_bf16( \
            AV[mi][kh], BV1[ni][kh], acc[(MH)*4+mi][2+ni], 0, 0, 0); \
      } \
  __builtin_amdgcn_s_setprio(0); \
} while (0)

#define LGKM0 do { \
  asm volatile("s_waitcnt lgkmcnt(0)" ::: "memory"); \
  __builtin_amdgcn_sched_barrier(0); \
} while (0)
#define VMC(N) asm volatile("s_waitcnt vmcnt(" #N ")" ::: "memory")
#define BAR() __builtin_amdgcn_s_barrier()

// C = A(16384 x 1024 bf16, ld ALD) @ B^T (B stored N x 1024 bf16 rm).
// 256x256 tile, 8 waves (2Mx4N). 4 merged phases / 2-K-chunk iteration, ONE
// barrier per phase: {reads; stage; lgkm0; MFMA x32; [vmcnt]; BAR}.
// vmcnt(4) at mph2/mph4 only. Hazard table verified r9/r11 (journal).
// EPI 0: QKV epilogue (phi cols<2048, mask on K cols), bf16 C (ld 3072), aux=mask
// EPI 1: plain fp32 C (ld NTOT)
template<int NTOT, int EPI, int ALD, int NT, int PERB>
__device__ __forceinline__ void gemm_body(
    const u16* __restrict__ A, const u16* __restrict__ Bm,
    void* __restrict__ C, const float* __restrict__ aux) {
  __shared__ u16 As[2][2][8192];   // [kchunk parity][row-half][128 x 64]
  __shared__ u16 Bs[2][2][8192];
  const int t = threadIdx.x;
  const int l = t & 63;
  const int w = t >> 6;
  const int rl = l & 15, kg = l >> 4;
  const int wm = w >> 2, wn = w & 3;      // 2M x 4N waves
  constexpr int nbn = NTOT / 256;
  constexpr int nwg = 64 * nbn;           // total output tiles
  constexpr int GRID = nwg / NT;          // blocks launched
  constexpr int KC = NT * 16;             // K-chunks (64 wide) per block
  constexpr int IT = KC / 2;              // iterations (2 chunks each)
  static_assert(nwg % 8 == 0, "bijective xcd swizzle");
  const int bid = blockIdx.x;

  auto tcoord = [&](int ot, long& tar, long& tbr) {
    const int gt = ot * GRID + bid;
    const int swz = (gt & 7) * (nwg / 8) + (gt >> 3);
    tar = (long)(swz / nbn) * 256;
    tbr = (long)(swz % nbn) * 256;
  };
  auto asrc = [&](int ch) {
    long ta, tb; tcoord(ch >> 4, ta, tb);
    return A + ta * ALD + (ch & 15) * 64;
  };
  auto bsrc = [&](int ch) {
    long ta, tb; tcoord(ch >> 4, ta, tb);
    return Bm + (PERB ? (ta >> 12) * 1048576 : 0) + tb * 1024 + (ch & 15) * 64;
  };

  f32x4 acc[8][4];
  #pragma unroll
  for (int i = 0; i < 8; ++i)
    #pragma unroll
    for (int j = 0; j < 4; ++j)
      acc[i][j] = (f32x4){0.f, 0.f, 0.f, 0.f};

  bf16x8 afA[4][2], bA[2][2], bB[2][2];

  auto epilogue = [&](int ot) {
    long ar0, br0; tcoord(ot, ar0, br0);
    #pragma unroll
    for (int mh = 0; mh < 2; ++mh)
      #pragma unroll
      for (int mi = 0; mi < 4; ++mi)
        #pragma unroll
        for (int j = 0; j < 4; ++j) {
          const long row = ar0 + mh*128 + wm*64 + mi*16 + kg*4 + j;
          float rs = 0.f;
          if (EPI == 0) rs = aux[row];            // mask[token]
          #pragma unroll
          for (int nh = 0; nh < 2; ++nh)
            #pragma unroll
            for (int ni = 0; ni < 2; ++ni) {
              const long col = br0 + nh*128 + wn*32 + ni*16 + rl;
              float v = acc[mh*4+mi][nh*2+ni][j];
              if (EPI == 0) {
                if (col < 2048) {                  // Q or K: phi = elu(x)+1
                  v = (v > 0.f) ? (v + 1.f) : __expf(v);
                  if (col >= 1024) v *= rs;        // K: * mask[token]
                }
                ((u16*)C)[row * QKVN + col] = f2bf(v);
              } else {
                ((float*)C)[row * NTOT + col] = v;
              }
            }
        }
    #pragma unroll
    for (int i = 0; i < 8; ++i)
      #pragma unroll
      for (int j = 0; j < 4; ++j)
        acc[i][j] = (f32x4){0.f, 0.f, 0.f, 0.f};
  };

  // Prologue: chunk0 all 4 halves + chunk1 h0 pair (h1 pair staged at mph1).
  {
    const u16* A0s = asrc(0); const u16* B0s = bsrc(0);
    const u16* A1s = asrc(1); const u16* B1s = bsrc(1);
    stage_half<ALD >(A0s,             As[0][0], t);
    stage_half<1024>(B0s,             Bs[0][0], t);
    stage_half<1024>(B0s + 128*1024,  Bs[0][1], t);
    stage_half<ALD >(A0s + 128*ALD,   As[0][1], t);
    stage_half<ALD >(A1s,             As[1][0], t);
    stage_half<1024>(B1s,             Bs[1][0], t);
    VMC(4);            // chunk0's 4 halves landed; chunk1 h0 pair in flight
    BAR();
  }

  for (int i = 0; i < IT; ++i) {
    const int o1 = 2*i + 1;
    const int e = (2*i + 2 < KC) ? 2*i + 2 : KC - 1;   // parity 0
    const int o = (2*i + 3 < KC) ? 2*i + 3 : KC - 1;   // parity 1
    const u16* Ao1 = asrc(o1); const u16* Bo1 = bsrc(o1);
    const u16* Ae = asrc(e);   const u16* Be = bsrc(e);
    const u16* Ao = asrc(o);   const u16* Bo = bsrc(o);

    // mph1: c0 M-half0 | stage c1 h1 pair (slots read prev-iter mph3/mph4)
    LDA_H(afA, As[0][0]); LDB_H(bA, Bs[0][0]); LDB_H(bB, Bs[0][1]);
    stage_half<ALD>(Ao1 + 128*ALD, As[1][1], t);
    stage_half<1024>(Bo1 + 128*1024, Bs[1][1], t);
    LGKM0;
    MFMA2Q(0, afA, bA, bB);
    BAR();                                   // no vmcnt here (drains at mph2)

    // mph2: c0 M-half1 | stage e h0 pair (slots read mph1)
    LDA_H(afA, As[0][1]);
    stage_half<ALD>(Ae, As[0][0], t);
    stage_half<1024>(Be, Bs[0][0], t);
    LGKM0;
    MFMA2Q(1, afA, bA, bB);
    VMC(4); BAR();                           // drains mph1 + prev-mph4 stages

    // mph3: c1 M-half0 | stage e h1 pair (As[0][1] read mph2, Bs[0][1] read mph1)
    LDA_H(afA, As[1][0]); LDB_H(bA, Bs[1][0]); LDB_H(bB, Bs[1][1]);
    stage_half<ALD>(Ae + 128*ALD, As[0][1], t);
    stage_half<1024>(Be + 128*1024, Bs[0][1], t);
    LGKM0;
    MFMA2Q(0, afA, bA, bB);
    BAR();                                   // no vmcnt here (drains at mph4)

    // mph4: c1 M-half1 | stage o h0 pair (slots read mph3)
    LDA_H(afA, As[1][1]);
    stage_half<ALD>(Ao, As[1][0], t);
    stage_half<1024>(Bo, Bs[1][0], t);
    LGKM0;
    MFMA2Q(1, afA, bA, bB);
    VMC(4); BAR();                           // drains mph2 + mph3 stages

    if ((i & 7) == 7) epilogue(i >> 3);
  }
  VMC(0);   // drain DMA before wave exit
}

// Distinct names so rocprof separates the two GEMMs.
__global__ __launch_bounds__(512, 2) void gemm_qkv(
    const u16* __restrict__ A, const u16* __restrict__ Bm,
    void* __restrict__ C, const float* __restrict__ aux) {
  gemm_body<3072, 0, 1024, 3, 0>(A, Bm, C, aux);
}
__global__ __launch_bounds__(512, 2) void gemm_out(
    const u16* __restrict__ A, const u16* __restrict__ Bm,
    void* __restrict__ C, const float* __restrict__ aux) {
  gemm_body<1024, 1, 1024, 1, 1>(A, Bm, C, aux);
}

// kv[bh][d][e] = sum_n K[n][d] * V[n][e];  ksum[bh][d] = sum_n K[n][d]
// 16 token-splits (grid 1024): K/V are L3-resident after gemm_qkv, so this is
// latency/occupancy-bound -> more blocks fill CUs and halve the tail.
__global__ __launch_bounds__(256) void kv_kernel(const u16* __restrict__ QKV,
    float* __restrict__ kvws, float* __restrict__ ksws) {
  __shared__ u16 Kl[32 * 64];
  __shared__ u16 Vl[32 * 64];
  const int t = threadIdx.x;
  const int l = t & 63, w = t >> 6;
  const int rl = l & 15, kg = l >> 4;
  const int bid = blockIdx.x;
  const int bh = bid >> 4, ns = bid & 15;
  const int b = bh >> 4, h = bh & 15;
  const long tok0 = (long)b * 4096 + ns * 256;

  f32x4 acc[4];
  #pragma unroll
  for (int i = 0; i < 4; ++i) acc[i] = (f32x4){0.f, 0.f, 0.f, 0.f};
  float ks = 0.f;
  const int srow = t >> 3, scc = t & 7;

  for (int it = 0; it < 8; ++it) {
    const long tb = tok0 + it * 32;
    g2l16(QKV + (tb + srow) * QKVN + 1024 + h * 64 + scc * 8, (char*)Kl + t * 16);
    g2l16(QKV + (tb + srow) * QKVN + 2048 + h * 64 + scc * 8, (char*)Vl + t * 16);
    __syncthreads();
    union { u16x8 u; bf16x8 v; } au, bu;
    #pragma unroll
    for (int j = 0; j < 8; ++j) au.u[j] = Kl[(kg * 8 + j) * 64 + w * 16 + rl];
    #pragma unroll
    for (int ni = 0; ni < 4; ++ni) {
      #pragma unroll
      for (int j = 0; j < 8; ++j) bu.u[j] = Vl[(kg * 8 + j) * 64 + ni * 16 + rl];
      acc[ni] = __builtin_amdgcn_mfma_f32_16x16x32_bf16(au.v, bu.v, acc[ni], 0, 0, 0);
    }
    #pragma unroll
    for (int r = 0; r < 8; ++r) ks += bf2f(Kl[(w * 8 + r) * 64 + (t & 63)]);
    __syncthreads();
  }
  float* kvb = kvws + bh * 4096;
  #pragma unroll
  for (int ni = 0; ni < 4; ++ni)
    #pragma unroll
    for (int j = 0; j < 4; ++j) {
      const int d = w * 16 + kg * 4 + j;
      const int e = ni * 16 + rl;
      atomicAdd(&kvb[d * 64 + e], acc[ni][j]);
    }
  atomicAdd(&ksws[bh * 64 + (t & 63)], ks);
}

// Merged post-kv small work. Blocks 0..1023: per-head normalize Q -> compact
// Qc (ld 1024). Blocks 1024..1279: W2T[b][o][hd] = sum_e kv[bh][d][e]*Wo[he][o].
__global__ __launch_bounds__(256) void finish_kernel(const u16* __restrict__ QKV,
    const float* __restrict__ ksws, const float* __restrict__ kvws,
    const float* __restrict__ Wo, u16* __restrict__ Qc, u16* __restrict__ W2T) {
  __shared__ float sh[4096];
  const int t = threadIdx.x;
  if (blockIdx.x < 1024) {
    const int bid = blockIdx.x;
    const int n0 = bid * 16;
    const int b = n0 >> 12;
    #pragma unroll
    for (int i = 0; i < 4; ++i) sh[i * 256 + t] = ksws[b * 1024 + i * 256 + t];
    __syncthreads();
    const int h = t & 15, ti = t >> 4;
    const u16* qp = QKV + (long)(n0 + ti) * QKVN + h * 64;
    u16* op = Qc + (long)(n0 + ti) * 1024 + h * 64;
    u16x8 v[8];
    float norm = 1e-6f;
    #pragma unroll
    for (int i = 0; i < 8; ++i) {
      v[i] = *(const u16x8*)(qp + i * 8);
      #pragma unroll
      for (int j = 0; j < 8; ++j) norm += bf2f(v[i][j]) * sh[h * 64 + i * 8 + j];
    }
    const float inv = 1.0f / norm;
    #pragma unroll
    for (int i = 0; i < 8; ++i) {
      u16x8 o;
      #pragma unroll
      for (int j = 0; j < 8; ++j) o[j] = f2bf(bf2f(v[i][j]) * inv);
      *(u16x8*)(op + i * 8) = o;
    }
  } else {
    const int bid = blockIdx.x - 1024;
    const int bh = bid >> 2, os = bid & 3;
    const int b = bh >> 4, h = bh & 15;
    const float* kvb = kvws + bh * 4096;
    #pragma unroll
    for (int i = 0; i < 16; ++i) sh[i * 256 + t] = kvb[i * 256 + t];
    __syncthreads();
    const int o = os * 256 + t;
    float wo[64];
    #pragma unroll
    for (int e = 0; e < 64; ++e) wo[e] = Wo[(long)(h * 64 + e) * 1024 + o];
    u16* out = W2T + (long)b * 1048576 + (long)o * 1024 + h * 64;
    for (int d = 0; d < 64; ++d) {
      float s = 0.f;
      #pragma unroll
      for (int e = 0; e < 64; ++e) s += wo[e] * sh[d * 64 + e];
      out[d] = f2bf(s);
    }
  }
}

// Merged prep. Blocks 0..255: WqkvT rows 0..2047 = (W{q,k}@blockdiag(proj))^T.
// Blocks 256..511: WqkvT rows 2048..3071 = Wv^T (64x64 tiled transpose).
// Blocks 512..8703: x (fp32) -> xb (bf16), 8 elems/thread.
__global__ __launch_bounds__(256) void prep_w(const float* __restrict__ Wq,
    const float* __restrict__ Wk, const float* __restrict__ proj,
    const float* __restrict__ Wv, const float* __restrict__ x,
    u16* __restrict__ WqkvT, u16* __restrict__ xb) {
  __shared__ float Wl[128][65];
  __shared__ float Pl[64][65];
  const int t = threadIdx.x;
  if (blockIdx.x >= 512) {
    const int idx = (blockIdx.x - 512) * 256 + t;
    const float4* p = (const float4*)x + (long)idx * 2;
    const float4 a = p[0], b = p[1];
    u16x8 o;
    o[0] = f2bf(a.x); o[1] = f2bf(a.y); o[2] = f2bf(a.z); o[3] = f2bf(a.w);
    o[4] = f2bf(b.x); o[5] = f2bf(b.y); o[6] = f2bf(b.z); o[7] = f2bf(b.w);
    *((u16x8*)xb + idx) = o;
    return;
  }
  if (blockIdx.x < 256) {
    const int bid = blockIdx.x;
    const int m = bid >> 7, h = (bid >> 3) & 15, cb = bid & 7;
    const float* W = m ? Wk : Wq;
    #pragma unroll
    for (int i = 0; i < 16; ++i) {
      const int idx = i * 256 + t;
      Pl[idx >> 6][idx & 63] = proj[idx];
    }
    #pragma unroll
    for (int i = 0; i < 32; ++i) {
      const int idx = i * 256 + t;
      const int c = idx >> 6, d = idx & 63;
      Wl[c][d] = W[(long)(cb * 128 + c) * 1024 + h * 64 + d];
    }
    __syncthreads();
    const int c = t & 127, j0 = (t >> 7) * 32;
    float a[32];
    #pragma unroll
    for (int jj = 0; jj < 32; ++jj) a[jj] = 0.f;
    for (int d = 0; d < 64; ++d) {
      const float wv = Wl[c][d];
      #pragma unroll
      for (int jj = 0; jj < 32; ++jj) a[jj] += wv * Pl[d][j0 + jj];
    }
    #pragma unroll
    for (int jj = 0; jj < 32; ++jj)
      WqkvT[(long)(m * 1024 + h * 64 + j0 + jj) * 1024 + cb * 128 + c] = f2bf(a[jj]);
  } else {
    const int bid = blockIdx.x - 256;
    const int rt = (bid >> 4) & 15, ct = bid & 15;
    const int j = t & 63;
    #pragma unroll
    for (int p = 0; p < 16; ++p) {
      const int i = p * 4 + (t >> 6);
      Wl[i][j] = Wv[(long)(rt * 64 + i) * 1024 + ct * 64 + j];
    }
    __syncthreads();
    u16* dst = WqkvT + (long)2048 * 1024;
    #pragma unroll
    for (int p = 0; p < 16; ++p) {
      const int i = p * 4 + (t >> 6);
      dst[(long)(ct * 64 + i) * 1024 + rt * 64 + j] = f2bf(Wl[j][i]);
    }
  }
}

extern "C" void kernel_launch(void* const* d_in, const int* in_sizes, int n_in,
                              void* d_out, int out_size, void* d_ws, size_t ws_size,
                              hipStream_t stream) {
  const float* x    = (const float*)d_in[0];
  const float* mask = (const float*)d_in[1];
  const float* Wq   = (const float*)d_in[2];
  const float* Wk   = (const float*)d_in[3];
  const float* Wv   = (const float*)d_in[4];
  const float* Wo   = (const float*)d_in[5];
  const float* proj = (const float*)d_in[6];

  char* ws = (char*)d_ws;
  u16*  WqkvT = (u16*)(ws);                    // 3072x1024 bf16 = 6 MB
  u16*  xb    = (u16*)(ws + 8388608);          // 16384x1024 bf16 = 32 MB
  u16*  QKV   = (u16*)(ws + 41943040);         // 16384x3072 bf16 = 96 MB
  float* kvws = (float*)(ws + 142606336);      // 64*64*64 f32 = 1 MB
  float* ksws = (float*)(ws + 143654912);      // 64*64 f32 = 16 KB
  // Dead-region reuse (stream-ordered, race-free):
  u16*  Qc   = xb;                             // xb dead after QKV GEMM
  u16*  W2T  = (u16*)(ws);                     // WqkvT dead after QKV GEMM (8 MB)
  if (ws_size < (size_t)143671296) return;

  hipMemsetAsync(kvws, 0, 1064960, stream);
  prep_w<<<8704, 256, 0, stream>>>(Wq, Wk, proj, Wv, x, WqkvT, xb);
  gemm_qkv<<<256, 512, 0, stream>>>(xb, WqkvT, (void*)QKV, mask);
  kv_kernel<<<1024, 256, 0, stream>>>(QKV, kvws, ksws);
  finish_kernel<<<1280, 256, 0, stream>>>(QKV, ksws, kvws, Wo, Qc, W2T);
  gemm_out<<<256, 512, 0, stream>>>(Qc, W2T, d_out, nullptr);
}